// Round 12
// baseline (136.648 us; speedup 1.0000x reference)
//
#include <hip/hip_runtime.h>
#include <hip/hip_bf16.h>
#include <stdint.h>

typedef __attribute__((ext_vector_type(8)))  short short8;
typedef __attribute__((ext_vector_type(4)))  float floatx4;
typedef __attribute__((ext_vector_type(16))) float floatx16;

#define S_LEN 2048
#define DH    128
#define BQ    64
#define BKV   64
#define NSTEP (S_LEN / BKV)
#define SCALE 0.08838834764831845f                  // 1/sqrt(128)
#define SCALE2 0.12753785429791905f                 // SCALE * log2(e)
#define DTHR 11.541560327111708f                    // 8 * log2(e)

__device__ __forceinline__ float ex2(float x) { return __builtin_amdgcn_exp2f(x); }

__device__ __forceinline__ unsigned short f2b(float f) {
    union { float f; unsigned u; } v; v.f = f;
    unsigned r = v.u + 0x7fffu + ((v.u >> 16) & 1u);
    return (unsigned short)(r >> 16);
}

__device__ __forceinline__ unsigned cvt_pk(float lo, float hi) {
    unsigned r;
    asm("v_cvt_pk_bf16_f32 %0, %1, %2" : "=v"(r) : "v"(lo), "v"(hi));
    return r;
}

__device__ __forceinline__ void gll16(const void* g, void* l) {
    __builtin_amdgcn_global_load_lds(
        (__attribute__((address_space(1))) void*)(g),
        (__attribute__((address_space(3))) void*)(l), 16, 0, 0);
}

// ============================ prepass kernels ============================

__global__ __launch_bounds__(256) void conv_k(const float* __restrict__ K,
                                              unsigned short* __restrict__ Kbf)
{
    int i = blockIdx.x * 256 + threadIdx.x;
    float4 v = ((const float4*)K)[i];
    ushort4 o;
    o.x = f2b(v.x); o.y = f2b(v.y); o.z = f2b(v.z); o.w = f2b(v.w);
    ((ushort4*)Kbf)[i] = o;
}

__global__ __launch_bounds__(256) void transp_v(const float* __restrict__ V,
                                                unsigned short* __restrict__ Vt)
{
    __shared__ float t[32][33];
    const int k0 = blockIdx.x * 32, d0 = blockIdx.y * 32, b = blockIdx.z;
    const int tx = threadIdx.x & 31, ty = threadIdx.x >> 5;
    const float* Vb = V + ((size_t)b * S_LEN + k0) * DH + d0;
    #pragma unroll
    for (int i = 0; i < 4; ++i)
        t[ty + 8 * i][tx] = Vb[(size_t)(ty + 8 * i) * DH + tx];
    __syncthreads();
    unsigned short* Vtb = Vt + ((size_t)b * DH + d0) * S_LEN + k0;
    #pragma unroll
    for (int i = 0; i < 4; ++i)
        Vtb[(size_t)(ty + 8 * i) * S_LEN + tx] = f2b(t[tx][ty + 8 * i]);
}

// mask bit-pack: row-per-wave streaming. Group it covers ints [256it,256it+256);
// word c bit l <-> int(256it + 4l + c). Coalesced 1KB per load instruction.
__global__ __launch_bounds__(256) void pack_mask(const int* __restrict__ M,
                                                 unsigned long long* __restrict__ P)
{
    const int lane = threadIdx.x & 63;
    const int wv   = threadIdx.x >> 6;
    const int row  = blockIdx.x * 4 + wv;            // 0 .. B*S-1
    const int* Mr  = M + (size_t)row * S_LEN;
    unsigned long long* Pr = P + (size_t)row * 32;
    #pragma unroll
    for (int it = 0; it < 8; ++it) {
        int4 v = *(const int4*)(Mr + it * 256 + lane * 4);
        unsigned long long b0 = __ballot(v.x != 0);
        unsigned long long b1 = __ballot(v.y != 0);
        unsigned long long b2 = __ballot(v.z != 0);
        unsigned long long b3 = __ballot(v.w != 0);
        if (lane == 0) {
            Pr[it * 4 + 0] = b0;
            Pr[it * 4 + 1] = b1;
            Pr[it * 4 + 2] = b2;
            Pr[it * 4 + 3] = b3;
        }
    }
}

// ============================ main kernel ============================
// 32x32 MFMA; wave (wq,wk): q-half wq, kv-half wk. S^T = mfma(K,Q);
// O^T = mfma(V^T,P). P exchanged in-register. Mask consumed as packed bits
// (32B per lane per 4 steps, L3-resident). Per-wave (m,l,accO); end merge.
// LDS: KH0 0..16384, KH1 16384..32768 (K dbuf, gll, source (r&15)<<4 swz)
//      VT0 32768..51200, VT1 51200..69632 (V^T dbuf, 128 rows x 144B)
#define LDS_BYTES 69632

__global__ __launch_bounds__(256, 2)
void attn_fwd(const float* __restrict__ Q, const unsigned short* __restrict__ Kbf,
              const unsigned short* __restrict__ Vt,
              const unsigned long long* __restrict__ Pm,
              float* __restrict__ O)
{
    __shared__ __align__(128) char lds[LDS_BYTES];

    const int tid  = threadIdx.x;
    const int lane = tid & 63;
    const int w    = tid >> 6;
    const int wq   = w & 1;              // q-half
    const int wk   = w >> 1;             // kv-half
    const int lq   = lane & 31;          // q col (lane-local)
    const int hi   = lane >> 5;
    const int qt   = blockIdx.x;
    const int b    = blockIdx.y;
    const int q0   = qt * BQ;

    const int vd = tid & 127;            // V^T row (d) this thread stages
    const int vh = tid >> 7;             // k-half (0/1)
    const int krow_l = lane >> 4;
    const int kcol_l = (lane & 15) * 16;

    // ---- Q B-fragments (scale*log2e folded): qf[dsub] = Q[q][d=16dsub+8hi+e]
    short8 qf[8];
    {
        const float* qrow = Q + ((size_t)(b * S_LEN + q0 + wq * 32 + lq)) * DH;
        #pragma unroll
        for (int dsub = 0; dsub < 8; ++dsub) {
            const float* p = qrow + dsub * 16 + hi * 8;
            float4 a  = *(const float4*)(p);
            float4 bb = *(const float4*)(p + 4);
            short8 f;
            f[0] = f2b(a.x * SCALE2);  f[1] = f2b(a.y * SCALE2);
            f[2] = f2b(a.z * SCALE2);  f[3] = f2b(a.w * SCALE2);
            f[4] = f2b(bb.x * SCALE2); f[5] = f2b(bb.y * SCALE2);
            f[6] = f2b(bb.z * SCALE2); f[7] = f2b(bb.w * SCALE2);
            qf[dsub] = f;
        }
    }

    float m_run = -1e30f;
    float l_run = 0.f;
    floatx16 accO[4];
    #pragma unroll
    for (int i = 0; i < 4; ++i) accO[i] = (floatx16)(0.f);

    const char*           Kb8 = (const char*)(Kbf + (size_t)b * S_LEN * DH);
    const unsigned short* Vtb = Vt + (size_t)b * DH * S_LEN;
    // packed mask row for this lane's q
    const unsigned long long* Pk = Pm
        + ((size_t)(b * S_LEN + q0 + wq * 32 + lq) << 5);

    short8 vreg[4];
    unsigned long long mgc[4], mgn[4];

#define LOAD_MG(DST, G) {                                                     \
    ulonglong2 a_ = *(const ulonglong2*)(Pk + (G) * 4);                       \
    ulonglong2 b_ = *(const ulonglong2*)(Pk + (G) * 4 + 2);                   \
    DST[0] = a_.x; DST[1] = a_.y; DST[2] = b_.x; DST[3] = b_.y; }

    // ---- prologue
    #pragma unroll
    for (int i = 0; i < 4; ++i) {                    // K(0) -> KH0
        int j = (w << 2) | i;
        int r = 4 * j + krow_l;
        unsigned cb = (unsigned)kcol_l ^ (unsigned)((r & 15) << 4);
        gll16(Kb8 + (size_t)r * 256 + cb, lds + j * 1024);
    }
    #pragma unroll
    for (int j = 0; j < 4; ++j)                      // V(0) -> regs
        vreg[j] = *(const short8*)(Vtb + (size_t)vd * S_LEN + vh * 32 + j * 8);
    #pragma unroll
    for (int j = 0; j < 4; ++j)                      // -> VT0
        *(short8*)(lds + 32768 + vd * 144 + vh * 64 + j * 16) = vreg[j];
    #pragma unroll
    for (int j = 0; j < 4; ++j)                      // vreg = V(1)
        vreg[j] = *(const short8*)(Vtb + (size_t)vd * S_LEN + BKV + vh * 32 + j * 8);
    LOAD_MG(mgc, 0);
    LOAD_MG(mgn, 1);
    __syncthreads();

#define STEP_BODY(T, TT) {                                                    \
    const int pb  = (T) & 1;                                                  \
    const int kv0 = (T) * BKV;                                                \
    /* gll K(T+1) -> KH[pb^1] */                                              \
    if ((T) + 1 < NSTEP) {                                                    \
        const char* Ksrc = Kb8 + (size_t)(kv0 + BKV) * 256;                   \
        char* KHn = lds + ((pb ^ 1) * 16384);                                 \
        _Pragma("unroll")                                                     \
        for (int i = 0; i < 4; ++i) {                                         \
            int j = (w << 2) | i;                                             \
            int r = 4 * j + krow_l;                                           \
            unsigned cb = (unsigned)kcol_l ^ (unsigned)((r & 15) << 4);       \
            gll16(Ksrc + (size_t)r * 256 + cb, KHn + j * 1024);               \
        }                                                                     \
    }                                                                         \
    /* write VT[pb^1] = V(T+1); issue vreg = V(T+2) */                        \
    if ((T) + 1 < NSTEP) {                                                    \
        _Pragma("unroll")                                                     \
        for (int j = 0; j < 4; ++j)                                           \
            *(short8*)(lds + 32768 + (pb ^ 1) * 18432 + vd * 144 + vh * 64    \
                       + j * 16) = vreg[j];                                   \
    }                                                                         \
    if ((T) + 2 < NSTEP) {                                                    \
        const unsigned short* vs_ = Vtb + (size_t)vd * S_LEN                  \
                                   + (kv0 + 2 * BKV) + vh * 32;               \
        _Pragma("unroll")                                                     \
        for (int j = 0; j < 4; ++j)                                           \
            vreg[j] = *(const short8*)(vs_ + j * 8);                          \
    }                                                                         \
    /* QK^T: S^T[kv=wk*32+(row pat)][q=lq], 8 d-chunks into one acc */        \
    floatx16 accS = (floatx16)(0.f);                                          \
    {                                                                         \
        const char* KHp = lds + pb * 16384;                                   \
        const int krow = wk * 32 + lq;                                        \
        const char* kbase = KHp + krow * 256;                                 \
        const unsigned ksw = (unsigned)((krow & 15) << 4);                    \
        __builtin_amdgcn_s_setprio(1);                                        \
        _Pragma("unroll")                                                     \
        for (int dsub = 0; dsub < 8; ++dsub) {                                \
            short8 kf = *(const short8*)(kbase +                              \
                ((unsigned)(dsub * 32 + hi * 16) ^ ksw));                     \
            accS = __builtin_amdgcn_mfma_f32_32x32x16_bf16(                   \
                       kf, qf[dsub], accS, 0, 0, 0);                          \
        }                                                                     \
        __builtin_amdgcn_s_setprio(0);                                        \
    }                                                                         \
    /* softmax: mask bits from packed group regs */                           \
    const int base_ = (TT) * 16 + wk * 8 + hi;                                \
    unsigned mb0 = (unsigned)(mgc[0] >> base_);                               \
    unsigned mb1 = (unsigned)(mgc[1] >> base_);                               \
    unsigned mb2 = (unsigned)(mgc[2] >> base_);                               \
    unsigned mb3 = (unsigned)(mgc[3] >> base_);                               \
    float p_[16];                                                             \
    _Pragma("unroll")                                                         \
    for (int j = 0; j < 4; ++j) {                                             \
        p_[4*j+0] = ((mb0 >> (2*j)) & 1u) ? -1e30f : accS[4*j+0];             \
        p_[4*j+1] = ((mb1 >> (2*j)) & 1u) ? -1e30f : accS[4*j+1];             \
        p_[4*j+2] = ((mb2 >> (2*j)) & 1u) ? -1e30f : accS[4*j+2];             \
        p_[4*j+3] = ((mb3 >> (2*j)) & 1u) ? -1e30f : accS[4*j+3];             \
    }                                                                         \
    float mx = p_[0];                                                         \
    _Pragma("unroll")                                                         \
    for (int r = 1; r < 16; ++r) mx = fmaxf(mx, p_[r]);                       \
    mx = fmaxf(mx, __shfl_xor(mx, 32));                                       \
    int need = __any(mx - m_run > DTHR);                                      \
    float corr = 1.0f;                                                        \
    if (need) {                                                               \
        float mn = fmaxf(m_run, mx);                                          \
        corr = ex2(m_run - mn);                                               \
        m_run = mn;                                                           \
    }                                                                         \
    float ts = 0.f;                                                           \
    _Pragma("unroll")                                                         \
    for (int r = 0; r < 16; ++r) { p_[r] = ex2(p_[r] - m_run); ts += p_[r]; } \
    ts += __shfl_xor(ts, 32);                                                 \
    if (need) {                                                               \
        l_run = l_run * corr + ts;                                            \
        _Pragma("unroll")                                                     \
        for (int ds = 0; ds < 4; ++ds) {                                      \
            floatx16 o = accO[ds];                                            \
            _Pragma("unroll")                                                 \
            for (int r = 0; r < 16; ++r) o[r] *= corr;                        \
            accO[ds] = o;                                                     \
        }                                                                     \
    } else {                                                                  \
        l_run += ts;                                                          \
    }                                                                         \
    /* P B-frags via in-register half exchange (per kv-sub of 16) */          \
    short8 pf[2];                                                             \
    _Pragma("unroll")                                                         \
    for (int ks = 0; ks < 2; ++ks) {                                          \
        unsigned a01 = cvt_pk(p_[8*ks+0], p_[8*ks+1]);                        \
        unsigned a23 = cvt_pk(p_[8*ks+2], p_[8*ks+3]);                        \
        unsigned b01 = cvt_pk(p_[8*ks+4], p_[8*ks+5]);                        \
        unsigned b23 = cvt_pk(p_[8*ks+6], p_[8*ks+7]);                        \
        unsigned ta01 = (unsigned)__shfl_xor((int)a01, 32);                   \
        unsigned ta23 = (unsigned)__shfl_xor((int)a23, 32);                   \
        unsigned tb01 = (unsigned)__shfl_xor((int)b01, 32);                   \
        unsigned tb23 = (unsigned)__shfl_xor((int)b23, 32);                   \
        union { unsigned u[4]; short8 v; } pu;                                \
        pu.u[0] = hi ? tb01 : a01;                                            \
        pu.u[1] = hi ? tb23 : a23;                                            \
        pu.u[2] = hi ? b01 : ta01;                                            \
        pu.u[3] = hi ? b23 : ta23;                                            \
        pf[ks] = pu.v;                                                        \
    }                                                                         \
    /* PV: O^T[d=32ds+pat][q=lq] += V^T x P over this wave's kv-half */       \
    {                                                                         \
        const char* VTp = lds + 32768 + pb * 18432;                           \
        __builtin_amdgcn_s_setprio(1);                                        \
        _Pragma("unroll")                                                     \
        for (int ds = 0; ds < 4; ++ds) {                                      \
            const char* vbase = VTp + (ds * 32 + lq) * 144 + wk * 64 + hi*16; \
            _Pragma("unroll")                                                 \
            for (int ks = 0; ks < 2; ++ks) {                                  \
                short8 vf = *(const short8*)(vbase + ks * 32);                \
                accO[ds] = __builtin_amdgcn_mfma_f32_32x32x16_bf16(           \
                               vf, pf[ks], accO[ds], 0, 0, 0);                \
            }                                                                 \
        }                                                                     \
        __builtin_amdgcn_s_setprio(0);                                        \
    }                                                                         \
    __syncthreads(); }

    for (int g = 0; g < 8; ++g) {
        STEP_BODY(4 * g + 0, 0)
        STEP_BODY(4 * g + 1, 1)
        STEP_BODY(4 * g + 2, 2)
        STEP_BODY(4 * g + 3, 3)
        mgc[0] = mgn[0]; mgc[1] = mgn[1]; mgc[2] = mgn[2]; mgc[3] = mgn[3];
        if (g + 2 < 8) LOAD_MG(mgn, g + 2);
    }
#undef STEP_BODY
#undef LOAD_MG

    // ---- merge partials across wk pairs (reuse LDS; loop ended on barrier)
    {
        float* mg = (float*)lds;
        const int slot = (wq * 64 + lane) * 68;    // 64 accO + m + l (+2 pad)
        if (wk == 1) {
            #pragma unroll
            for (int ds = 0; ds < 4; ++ds)
                #pragma unroll
                for (int rr = 0; rr < 4; ++rr) {
                    float4 v;
                    v.x = accO[ds][4*rr+0]; v.y = accO[ds][4*rr+1];
                    v.z = accO[ds][4*rr+2]; v.w = accO[ds][4*rr+3];
                    *(float4*)(mg + slot + ds * 16 + rr * 4) = v;
                }
            mg[slot + 64] = m_run;
            mg[slot + 65] = l_run;
        }
        __syncthreads();
        if (wk == 0) {
            float m1 = mg[slot + 64], l1 = mg[slot + 65];
            float m  = fmaxf(m_run, m1);
            float f0 = ex2(m_run - m), f1 = ex2(m1 - m);
            float l  = l_run * f0 + l1 * f1;
            float inv = (l > 0.f) ? 1.f / l : 0.f;
            float* Ob = O + ((size_t)(b * S_LEN + q0 + wq * 32 + lq)) * DH;
            #pragma unroll
            for (int ds = 0; ds < 4; ++ds)
                #pragma unroll
                for (int rr = 0; rr < 4; ++rr) {
                    float4 part = *(const float4*)(mg + slot + ds * 16 + rr * 4);
                    float4 ov;
                    ov.x = (accO[ds][4*rr+0] * f0 + part.x * f1) * inv;
                    ov.y = (accO[ds][4*rr+1] * f0 + part.y * f1) * inv;
                    ov.z = (accO[ds][4*rr+2] * f0 + part.z * f1) * inv;
                    ov.w = (accO[ds][4*rr+3] * f0 + part.w * f1) * inv;
                    *(float4*)(Ob + ds * 32 + 8 * rr + 4 * hi) = ov;
                }
        }
    }
}

// ============================ fallback (verified round-3 kernel) ============================
#define FB_LDS_BYTES 77824

__global__ __launch_bounds__(256, 2)
void attn_fwd_fb(const float* __restrict__ Q, const float* __restrict__ K,
                 const float* __restrict__ V, const int* __restrict__ M,
                 float* __restrict__ O)
{
    __shared__ __align__(128) char lds[FB_LDS_BYTES];

    const int tid  = threadIdx.x;
    const int lane = tid & 63;
    const int w    = tid >> 6;
    const int c    = lane & 15;
    const int g    = lane >> 4;
    const int qt   = blockIdx.x;
    const int b    = blockIdx.y;
    const int q0   = qt * 64;

    const int rbase = tid >> 5;
    const int c4    = tid & 31;
    const unsigned swk = (unsigned)(c4 * 8) ^ (unsigned)(rbase << 4);
    const int vd    = tid & 127;
    const int vk0   = (tid >> 7) * 32;

    short8 qf[4];
    {
        const float* qrow = Q + ((size_t)(b * S_LEN + q0 + w * 16 + c)) * DH;
        #pragma unroll
        for (int dk = 0; dk < 4; ++dk) {
            const float* p = qrow + dk * 32 + g * 8;
            float4 a  = *(const float4*)(p);
            float4 bb = *(const float4*)(p + 4);
            short8 f;
            f[0] = f2b(a.x * SCALE);  f[1] = f2b(a.y * SCALE);
            f[2] = f2b(a.z * SCALE);  f[3] = f2b(a.w * SCALE);
            f[4] = f2b(bb.x * SCALE); f[5] = f2b(bb.y * SCALE);
            f[6] = f2b(bb.z * SCALE); f[7] = f2b(bb.w * SCALE);
            qf[dk] = f;
        }
    }

    float m_run[4] = {-1e30f, -1e30f, -1e30f, -1e30f};
    float l_run[4] = {0.f, 0.f, 0.f, 0.f};
    floatx4 accO[8];
    #pragma unroll
    for (int i = 0; i < 8; ++i) accO[i] = (floatx4)(0.f);

    const float* Kb = K + (size_t)b * S_LEN * DH;
    const float* Vb = V + (size_t)b * S_LEN * DH;
    const int*   Mb = M + (size_t)b * S_LEN * S_LEN + (size_t)q0 * S_LEN;

    size_t moff[4];
    #pragma unroll
    for (int r = 0; r < 4; ++r)
        moff[r] = (size_t)(w * 16 + 4 * g + r) * S_LEN;

    float4 kreg[8];
    float  vreg[32];
    int    mreg[16];

    #pragma unroll
    for (int i = 0; i < 8; ++i)
        kreg[i] = *(const float4*)(Kb + (size_t)(i * 8 + rbase) * DH + c4 * 4);
    #pragma unroll
    for (int j = 0; j < 32; ++j)
        vreg[j] = Vb[(size_t)(vk0 + j) * DH + vd];
    #pragma unroll
    for (int r = 0; r < 4; ++r)
        #pragma unroll
        for (int n = 0; n < 4; ++n)
            mreg[r * 4 + n] = Mb[moff[r] + n * 16 + c];

    #pragma unroll
    for (int i = 0; i < 8; ++i) {
        float4 kv = kreg[i];
        unsigned long long kp =
              (unsigned long long)f2b(kv.x)
            | ((unsigned long long)f2b(kv.y) << 16)
            | ((unsigned long long)f2b(kv.z) << 32)
            | ((unsigned long long)f2b(kv.w) << 48);
        *(unsigned long long*)(lds + (i * 8 + rbase) * 256 + swk) = kp;
    }
    {
        char* vbase = lds + 32768 + vd * 144 + vk0 * 2;
        #pragma unroll
        for (int i = 0; i < 4; ++i) {
            short8 pk;
            #pragma unroll
            for (int e = 0; e < 8; ++e) pk[e] = f2b(vreg[i * 8 + e]);
            *(short8*)(vbase + i * 16) = pk;
        }
    }
    #pragma unroll
    for (int i = 0; i < 8; ++i)
        kreg[i] = *(const float4*)(Kb + (size_t)(BKV + i * 8 + rbase) * DH + c4 * 4);
    #pragma unroll
    for (int j = 0; j < 32; ++j)
        vreg[j] = Vb[(size_t)(BKV + vk0 + j) * DH + vd];

    __syncthreads();

    char* psw = lds + 69632 + w * 2048;

    for (int step = 0; step < NSTEP; ++step) {
        const int p = step & 1;
        const int kv0 = step * BKV;
        char* KHp = lds + p * 16384;
        char* VTp = lds + 32768 + p * 18432;

        floatx4 accS[4];
        #pragma unroll
        for (int n = 0; n < 4; ++n) accS[n] = (floatx4)(0.f);
        #pragma unroll
        for (int n = 0; n < 4; ++n) {
            const char* krow = KHp + (n * 16 + c) * 256;
            #pragma unroll
            for (int dk = 0; dk < 4; ++dk) {
                unsigned colb = (unsigned)(dk * 64 + g * 16) ^ (unsigned)((c & 7) << 4);
                short8 kf = *(const short8*)(krow + colb);
                accS[n] = __builtin_amdgcn_mfma_f32_16x16x32_bf16(qf[dk], kf, accS[n], 0, 0, 0);
            }
        }

        float pv[4][4];
        float corr[4];
        #pragma unroll
        for (int r = 0; r < 4; ++r) {
            float sv[4];
            #pragma unroll
            for (int n = 0; n < 4; ++n) {
                float s = accS[n][r];
                if (mreg[r * 4 + n]) s = -1e30f;
                sv[n] = s;
            }
            float tm = fmaxf(fmaxf(sv[0], sv[1]), fmaxf(sv[2], sv[3]));
            #pragma unroll
            for (int off = 1; off < 16; off <<= 1)
                tm = fmaxf(tm, __shfl_xor(tm, off, 64));
            float mn = fmaxf(m_run[r], tm);
            corr[r]  = __expf(m_run[r] - mn);
            m_run[r] = mn;
            float ts = 0.f;
            #pragma unroll
            for (int n = 0; n < 4; ++n) { pv[n][r] = __expf(sv[n] - mn); ts += pv[n][r]; }
            #pragma unroll
            for (int off = 1; off < 16; off <<= 1)
                ts += __shfl_xor(ts, off, 64);
            l_run[r] = l_run[r] * corr[r] + ts;
        }
        if (step + 1 < NSTEP) {
            const int kvn = kv0 + BKV;
            #pragma unroll
            for (int r = 0; r < 4; ++r)
                #pragma unroll
                for (int n = 0; n < 4; ++n)
                    mreg[r * 4 + n] = Mb[moff[r] + kvn + n * 16 + c];
        }

        #pragma unroll
        for (int s8 = 0; s8 < 8; ++s8) {
            floatx4 o = accO[s8];
            o[0] *= corr[0]; o[1] *= corr[1]; o[2] *= corr[2]; o[3] *= corr[3];
            accO[s8] = o;
        }

        #pragma unroll
        for (int r = 0; r < 4; ++r) {
            int rl = 4 * g + r;
            #pragma unroll
            for (int n = 0; n < 4; ++n) {
                unsigned colb = (unsigned)((n * 16 + c) * 2) ^ (unsigned)((rl & 7) << 4);
                *(unsigned short*)(psw + rl * 128 + colb) = f2b(pv[n][r]);
            }
        }

        #pragma unroll
        for (int sub = 0; sub < 2; ++sub) {
            unsigned colb = (unsigned)(sub * 64 + g * 16) ^ (unsigned)((c & 7) << 4);
            short8 pf = *(const short8*)(psw + c * 128 + colb);
            #pragma unroll
            for (int s8 = 0; s8 < 8; ++s8) {
                short8 vf = *(const short8*)(VTp + (s8 * 16 + c) * 144 + sub * 64 + g * 16);
                accO[s8] = __builtin_amdgcn_mfma_f32_16x16x32_bf16(pf, vf, accO[s8], 0, 0, 0);
            }
        }

        if (step + 1 < NSTEP) {
            char* KHn = lds + (p ^ 1) * 16384;
            char* VTn = lds + 32768 + (p ^ 1) * 18432;
            #pragma unroll
            for (int i = 0; i < 8; ++i) {
                float4 kv = kreg[i];
                unsigned long long kp =
                      (unsigned long long)f2b(kv.x)
                    | ((unsigned long long)f2b(kv.y) << 16)
                    | ((unsigned long long)f2b(kv.z) << 32)
                    | ((unsigned long long)f2b(kv.w) << 48);
                *(unsigned long long*)(KHn + (i * 8 + rbase) * 256 + swk) = kp;
            }
            char* vbase = VTn + vd * 144 + vk0 * 2;
            #pragma unroll
            for (int i = 0; i < 4; ++i) {
                short8 pk;
                #pragma unroll
                for (int e = 0; e < 8; ++e) pk[e] = f2b(vreg[i * 8 + e]);
                *(short8*)(vbase + i * 16) = pk;
            }
            if (step + 2 < NSTEP) {
                const int kvn2 = kv0 + 2 * BKV;
                #pragma unroll
                for (int i = 0; i < 8; ++i)
                    kreg[i] = *(const float4*)(Kb + (size_t)(kvn2 + i * 8 + rbase) * DH + c4 * 4);
                #pragma unroll
                for (int j = 0; j < 32; ++j)
                    vreg[j] = Vb[(size_t)(kvn2 + vk0 + j) * DH + vd];
            }
        }
        __syncthreads();
    }

    float inv[4];
    #pragma unroll
    for (int r = 0; r < 4; ++r) inv[r] = (l_run[r] > 0.f) ? 1.f / l_run[r] : 0.f;
    float* Ob = O + ((size_t)(b * S_LEN + q0 + w * 16)) * DH;
    #pragma unroll
    for (int s8 = 0; s8 < 8; ++s8) {
        #pragma unroll
        for (int r = 0; r < 4; ++r) {
            Ob[(size_t)(4 * g + r) * DH + s8 * 16 + c] = accO[s8][r] * inv[r];
        }
    }
}

extern "C" void kernel_launch(void* const* d_in, const int* in_sizes, int n_in,
                              void* d_out, int out_size, void* d_ws, size_t ws_size,
                              hipStream_t stream) {
    const float* Q = (const float*)d_in[0];
    const float* K = (const float*)d_in[1];
    const float* V = (const float*)d_in[2];
    const int*   M = (const int*)d_in[3];
    float*       O = (float*)d_out;

    const size_t elems    = (size_t)16 * S_LEN * DH;           // per K/V tensor
    const size_t kv_bytes = elems * sizeof(unsigned short);    // 8.39 MB
    const size_t pm_bytes = (size_t)16 * S_LEN * 32 * 8;       // 8.39 MB
    if (ws_size >= 2 * kv_bytes + pm_bytes) {
        unsigned short*     Kbf = (unsigned short*)d_ws;
        unsigned short*     Vt  = (unsigned short*)d_ws + elems;
        unsigned long long* Pm  = (unsigned long long*)((char*)d_ws + 2 * kv_bytes);
        conv_k<<<dim3((unsigned)(elems / 4 / 256)), dim3(256), 0, stream>>>(K, Kbf);
        transp_v<<<dim3(S_LEN / 32, DH / 32, 16), dim3(256), 0, stream>>>(V, Vt);
        pack_mask<<<dim3(16 * S_LEN / 4), dim3(256), 0, stream>>>(M, Pm);
        attn_fwd<<<dim3(S_LEN / BQ, 16), dim3(256), 0, stream>>>(Q, Kbf, Vt, Pm, O);
    } else {
        attn_fwd_fb<<<dim3(S_LEN / 64, 16), dim3(256), 0, stream>>>(Q, K, V, M, O);
    }
}

// Round 13
// 123.545 us; speedup vs baseline: 1.1061x; 1.1061x over previous
//
#include <hip/hip_runtime.h>
#include <hip/hip_bf16.h>
#include <stdint.h>

typedef __attribute__((ext_vector_type(8)))  short short8;
typedef __attribute__((ext_vector_type(4)))  float floatx4;
typedef __attribute__((ext_vector_type(16))) float floatx16;

#define S_LEN 2048
#define DH    128
#define BQ    64
#define BKV   64
#define NSTEP (S_LEN / BKV)
#define SCALE 0.08838834764831845f                  // 1/sqrt(128)
#define SCALE2 0.12753785429791905f                 // SCALE * log2(e)
#define DTHR 11.541560327111708f                    // 8 * log2(e)

__device__ __forceinline__ float ex2(float x) { return __builtin_amdgcn_exp2f(x); }

__device__ __forceinline__ unsigned short f2b(float f) {
    union { float f; unsigned u; } v; v.f = f;
    unsigned r = v.u + 0x7fffu + ((v.u >> 16) & 1u);
    return (unsigned short)(r >> 16);
}

__device__ __forceinline__ unsigned cvt_pk(float lo, float hi) {
    unsigned r;
    asm("v_cvt_pk_bf16_f32 %0, %1, %2" : "=v"(r) : "v"(lo), "v"(hi));
    return r;
}

// ============================ prepass kernels ============================

// K fragment-major: frag F=(wk,dsub,hi,lq) of tile (b,T) holds
// K[b][kv=T*64+wk*32+lq][d=dsub*16+hi*8 .. +8] as 8 bf16 (16B).
__global__ __launch_bounds__(256) void kfrag_make(const float* __restrict__ K,
                                                  unsigned short* __restrict__ KF)
{
    const int T = blockIdx.x, b = blockIdx.y;
    const float* Kb = K + ((size_t)b * S_LEN + T * 64) * DH;
    unsigned short* out = KF + ((size_t)(b * 32 + T)) * 1024 * 8;
    #pragma unroll
    for (int i = 0; i < 4; ++i) {
        int F = i * 256 + threadIdx.x;       // 0..1023
        int lq = F & 31, h = (F >> 5) & 1, dsub = (F >> 6) & 7, wk = F >> 9;
        const float* src = Kb + (size_t)(wk * 32 + lq) * DH + dsub * 16 + h * 8;
        float4 a = *(const float4*)src, bb = *(const float4*)(src + 4);
        short8 f;
        f[0] = f2b(a.x);  f[1] = f2b(a.y);  f[2] = f2b(a.z);  f[3] = f2b(a.w);
        f[4] = f2b(bb.x); f[5] = f2b(bb.y); f[6] = f2b(bb.z); f[7] = f2b(bb.w);
        *(short8*)(out + (size_t)F * 8) = f;
    }
}

// V fragment-major: frag G=(b,T,ds,wk,ks,hi,lq) holds
// V[b][kv=T*64+wk*32+ks*16+hi*8+e][d=ds*32+lq], e=0..7 (transposed).
__global__ __launch_bounds__(256) void vfrag_make(const float* __restrict__ V,
                                                  unsigned short* __restrict__ VF)
{
    __shared__ float t[32][33];
    const int k0 = blockIdx.x * 32, d0 = blockIdx.y * 32, b = blockIdx.z;
    const int tx = threadIdx.x & 31, ty = threadIdx.x >> 5;
    const float* Vb = V + ((size_t)b * S_LEN + k0) * DH + d0;
    #pragma unroll
    for (int i = 0; i < 4; ++i)
        t[ty + 8 * i][tx] = Vb[(size_t)(ty + 8 * i) * DH + tx];   // t[kv][d]
    __syncthreads();
    if (threadIdx.x < 128) {
        const int lq = threadIdx.x & 31;
        const int h  = (threadIdx.x >> 5) & 1;
        const int ks = threadIdx.x >> 6;
        const int T = k0 >> 6, wk = (k0 >> 5) & 1, ds = d0 >> 5;
        short8 f;
        #pragma unroll
        for (int e = 0; e < 8; ++e)
            f[e] = f2b(t[ks * 16 + h * 8 + e][lq]);
        unsigned short* o = VF +
            ((((((size_t)(b * 32 + T) * 4 + ds) * 2 + wk) * 2 + ks) * 2 + h) * 32 + lq) * 8;
        *(short8*)o = f;
    }
}

// mask bit-pack (verified R12): group it covers ints [256it,256it+256);
// word c bit l <-> int(256it + 4l + c).
__global__ __launch_bounds__(256) void pack_mask(const int* __restrict__ M,
                                                 unsigned long long* __restrict__ P)
{
    const int lane = threadIdx.x & 63;
    const int wv   = threadIdx.x >> 6;
    const int row  = blockIdx.x * 4 + wv;
    const int* Mr  = M + (size_t)row * S_LEN;
    unsigned long long* Pr = P + (size_t)row * 32;
    #pragma unroll
    for (int it = 0; it < 8; ++it) {
        int4 v = *(const int4*)(Mr + it * 256 + lane * 4);
        unsigned long long b0 = __ballot(v.x != 0);
        unsigned long long b1 = __ballot(v.y != 0);
        unsigned long long b2 = __ballot(v.z != 0);
        unsigned long long b3 = __ballot(v.w != 0);
        if (lane == 0) {
            Pr[it * 4 + 0] = b0;
            Pr[it * 4 + 1] = b1;
            Pr[it * 4 + 2] = b2;
            Pr[it * 4 + 3] = b3;
        }
    }
}

// ============================ main kernel ============================
// No LDS / no barriers in the main loop: MFMA operands load straight from
// fragment-major global arrays (L2-resident). 32x32 MFMA; wave (wq,wk);
// S^T = mfma(K,Q); O^T = mfma(V^T,P); in-register P exchange; packed mask
// bits; per-wave (m,l,accO); one LDS merge across wk at the end.
#define LDS_BYTES 34816

__global__ __launch_bounds__(256, 2)
void attn_fwd(const float* __restrict__ Q, const unsigned short* __restrict__ KF,
              const unsigned short* __restrict__ VF,
              const unsigned long long* __restrict__ Pm,
              float* __restrict__ O)
{
    __shared__ __align__(128) char lds[LDS_BYTES];

    const int tid  = threadIdx.x;
    const int lane = tid & 63;
    const int w    = tid >> 6;
    const int wq   = w & 1;
    const int wk   = w >> 1;
    const int lq   = lane & 31;
    const int hi   = lane >> 5;
    const int qt   = blockIdx.x;
    const int b    = blockIdx.y;
    const int q0   = qt * BQ;

    // ---- Q B-fragments (scale*log2e folded)
    short8 qf[8];
    {
        const float* qrow = Q + ((size_t)(b * S_LEN + q0 + wq * 32 + lq)) * DH;
        #pragma unroll
        for (int dsub = 0; dsub < 8; ++dsub) {
            const float* p = qrow + dsub * 16 + hi * 8;
            float4 a  = *(const float4*)(p);
            float4 bb = *(const float4*)(p + 4);
            short8 f;
            f[0] = f2b(a.x * SCALE2);  f[1] = f2b(a.y * SCALE2);
            f[2] = f2b(a.z * SCALE2);  f[3] = f2b(a.w * SCALE2);
            f[4] = f2b(bb.x * SCALE2); f[5] = f2b(bb.y * SCALE2);
            f[6] = f2b(bb.z * SCALE2); f[7] = f2b(bb.w * SCALE2);
            qf[dsub] = f;
        }
    }

    float m_run = -1e30f;
    float l_run = 0.f;
    floatx16 accO[4];
    #pragma unroll
    for (int i = 0; i < 4; ++i) accO[i] = (floatx16)(0.f);

    // per-lane fragment bases (ushort units)
    // Kfrag: (((((b*32+T)*2+wk)*8+dsub)*2+hi)*32+lq)*8
    const unsigned short* KFl = KF + (((size_t)(b * 32) * 2 + wk) * 512
                                      + (size_t)hi * 32 + lq) * 8;
    // per T advance: 2*512*8 ushorts; per dsub: 2*32*8 = 512 ushorts
    // Vfrag: ((((((b*32+T)*4+ds)*2+wk)*2+ks)*2+hi)*32+lq)*8
    const unsigned short* VFl = VF + ((((size_t)(b * 32) * 4 * 2 + wk) * 2) * 2 * 32
                                      + (size_t)hi * 32 + lq) * 8;
    // per T advance: 4*2*2*2*32*8; per ds: 2*2*2*32*8? (computed inline below)

    const unsigned long long* Pk = Pm
        + ((size_t)(b * S_LEN + q0 + wq * 32 + lq) << 5);

    unsigned long long mgc[4], mgn[4];
    short8 kfA[8], kfB[8], vfc[8];

#define LOAD_MG(DST, G) {                                                     \
    ulonglong2 a_ = *(const ulonglong2*)(Pk + (G) * 4);                       \
    ulonglong2 b_ = *(const ulonglong2*)(Pk + (G) * 4 + 2);                   \
    DST[0] = a_.x; DST[1] = a_.y; DST[2] = b_.x; DST[3] = b_.y; }

#define LOAD_KF(DST, T) {                                                     \
    const unsigned short* kp_ = KFl + (size_t)(T) * (2 * 512 * 8);            \
    _Pragma("unroll")                                                         \
    for (int dsub = 0; dsub < 8; ++dsub)                                      \
        DST[dsub] = *(const short8*)(kp_ + dsub * 512);                       \
}

#define LOAD_VF(T) {                                                          \
    _Pragma("unroll")                                                         \
    for (int ds = 0; ds < 4; ++ds)                                            \
        _Pragma("unroll")                                                     \
        for (int ks = 0; ks < 2; ++ks)                                        \
            vfc[ds * 2 + ks] = *(const short8*)(VFl                           \
                + ((size_t)(T) * 16 + ds * 4 + ks) * (2 * 32 * 8));           \
}

    // ---- prologue
    LOAD_KF(kfA, 0);
    LOAD_MG(mgc, 0);
    LOAD_MG(mgn, 1);

#define STEP_BODY(T, TT, KFC, KFN) {                                          \
    if ((T) + 1 < NSTEP) LOAD_KF(KFN, (T) + 1);                               \
    LOAD_VF(T);                                                               \
    /* QK^T */                                                                \
    floatx16 accS = (floatx16)(0.f);                                          \
    __builtin_amdgcn_s_setprio(1);                                            \
    _Pragma("unroll")                                                         \
    for (int dsub = 0; dsub < 8; ++dsub)                                      \
        accS = __builtin_amdgcn_mfma_f32_32x32x16_bf16(                       \
                   KFC[dsub], qf[dsub], accS, 0, 0, 0);                       \
    __builtin_amdgcn_s_setprio(0);                                            \
    /* softmax with packed mask bits */                                       \
    const int base_ = (TT) * 16 + wk * 8 + hi;                                \
    unsigned mb0 = (unsigned)(mgc[0] >> base_);                               \
    unsigned mb1 = (unsigned)(mgc[1] >> base_);                               \
    unsigned mb2 = (unsigned)(mgc[2] >> base_);                               \
    unsigned mb3 = (unsigned)(mgc[3] >> base_);                               \
    float p_[16];                                                             \
    _Pragma("unroll")                                                         \
    for (int j = 0; j < 4; ++j) {                                             \
        p_[4*j+0] = ((mb0 >> (2*j)) & 1u) ? -1e30f : accS[4*j+0];             \
        p_[4*j+1] = ((mb1 >> (2*j)) & 1u) ? -1e30f : accS[4*j+1];             \
        p_[4*j+2] = ((mb2 >> (2*j)) & 1u) ? -1e30f : accS[4*j+2];             \
        p_[4*j+3] = ((mb3 >> (2*j)) & 1u) ? -1e30f : accS[4*j+3];             \
    }                                                                         \
    float mx = p_[0];                                                         \
    _Pragma("unroll")                                                         \
    for (int r = 1; r < 16; ++r) mx = fmaxf(mx, p_[r]);                       \
    mx = fmaxf(mx, __shfl_xor(mx, 32));                                       \
    int need = __any(mx - m_run > DTHR);                                      \
    float corr = 1.0f;                                                        \
    if (need) {                                                               \
        float mn = fmaxf(m_run, mx);                                          \
        corr = ex2(m_run - mn);                                               \
        m_run = mn;                                                           \
    }                                                                         \
    float ts = 0.f;                                                           \
    _Pragma("unroll")                                                         \
    for (int r = 0; r < 16; ++r) { p_[r] = ex2(p_[r] - m_run); ts += p_[r]; } \
    ts += __shfl_xor(ts, 32);                                                 \
    if (need) {                                                               \
        l_run = l_run * corr + ts;                                            \
        _Pragma("unroll")                                                     \
        for (int ds = 0; ds < 4; ++ds) {                                      \
            floatx16 o = accO[ds];                                            \
            _Pragma("unroll")                                                 \
            for (int r = 0; r < 16; ++r) o[r] *= corr;                        \
            accO[ds] = o;                                                     \
        }                                                                     \
    } else {                                                                  \
        l_run += ts;                                                          \
    }                                                                         \
    /* P B-frags via in-register half exchange */                             \
    short8 pf[2];                                                             \
    _Pragma("unroll")                                                         \
    for (int ks = 0; ks < 2; ++ks) {                                          \
        unsigned a01 = cvt_pk(p_[8*ks+0], p_[8*ks+1]);                        \
        unsigned a23 = cvt_pk(p_[8*ks+2], p_[8*ks+3]);                        \
        unsigned b01 = cvt_pk(p_[8*ks+4], p_[8*ks+5]);                        \
        unsigned b23 = cvt_pk(p_[8*ks+6], p_[8*ks+7]);                        \
        unsigned ta01 = (unsigned)__shfl_xor((int)a01, 32);                   \
        unsigned ta23 = (unsigned)__shfl_xor((int)a23, 32);                   \
        unsigned tb01 = (unsigned)__shfl_xor((int)b01, 32);                   \
        unsigned tb23 = (unsigned)__shfl_xor((int)b23, 32);                   \
        union { unsigned u[4]; short8 v; } pu;                                \
        pu.u[0] = hi ? tb01 : a01;                                            \
        pu.u[1] = hi ? tb23 : a23;                                            \
        pu.u[2] = hi ? b01 : ta01;                                            \
        pu.u[3] = hi ? b23 : ta23;                                            \
        pf[ks] = pu.v;                                                        \
    }                                                                         \
    /* PV */                                                                  \
    __builtin_amdgcn_s_setprio(1);                                            \
    _Pragma("unroll")                                                         \
    for (int ds = 0; ds < 4; ++ds)                                            \
        _Pragma("unroll")                                                     \
        for (int ks = 0; ks < 2; ++ks)                                        \
            accO[ds] = __builtin_amdgcn_mfma_f32_32x32x16_bf16(               \
                           vfc[ds * 2 + ks], pf[ks], accO[ds], 0, 0, 0);      \
    __builtin_amdgcn_s_setprio(0);                                            \
}

    for (int g = 0; g < 8; ++g) {
        STEP_BODY(4 * g + 0, 0, kfA, kfB)
        STEP_BODY(4 * g + 1, 1, kfB, kfA)
        STEP_BODY(4 * g + 2, 2, kfA, kfB)
        STEP_BODY(4 * g + 3, 3, kfB, kfA)
        mgc[0] = mgn[0]; mgc[1] = mgn[1]; mgc[2] = mgn[2]; mgc[3] = mgn[3];
        if (g + 2 < 8) LOAD_MG(mgn, g + 2);
    }
#undef STEP_BODY
#undef LOAD_KF
#undef LOAD_VF
#undef LOAD_MG

    // ---- merge partials across wk pairs
    {
        float* mg = (float*)lds;
        const int slot = (wq * 64 + lane) * 68;
        if (wk == 1) {
            #pragma unroll
            for (int ds = 0; ds < 4; ++ds)
                #pragma unroll
                for (int rr = 0; rr < 4; ++rr) {
                    float4 v;
                    v.x = accO[ds][4*rr+0]; v.y = accO[ds][4*rr+1];
                    v.z = accO[ds][4*rr+2]; v.w = accO[ds][4*rr+3];
                    *(float4*)(mg + slot + ds * 16 + rr * 4) = v;
                }
            mg[slot + 64] = m_run;
            mg[slot + 65] = l_run;
        }
        __syncthreads();
        if (wk == 0) {
            float m1 = mg[slot + 64], l1 = mg[slot + 65];
            float m  = fmaxf(m_run, m1);
            float f0 = ex2(m_run - m), f1 = ex2(m1 - m);
            float l  = l_run * f0 + l1 * f1;
            float inv = (l > 0.f) ? 1.f / l : 0.f;
            float* Ob = O + ((size_t)(b * S_LEN + q0 + wq * 32 + lq)) * DH;
            #pragma unroll
            for (int ds = 0; ds < 4; ++ds)
                #pragma unroll
                for (int rr = 0; rr < 4; ++rr) {
                    float4 part = *(const float4*)(mg + slot + ds * 16 + rr * 4);
                    float4 ov;
                    ov.x = (accO[ds][4*rr+0] * f0 + part.x * f1) * inv;
                    ov.y = (accO[ds][4*rr+1] * f0 + part.y * f1) * inv;
                    ov.z = (accO[ds][4*rr+2] * f0 + part.z * f1) * inv;
                    ov.w = (accO[ds][4*rr+3] * f0 + part.w * f1) * inv;
                    *(float4*)(Ob + ds * 32 + 8 * rr + 4 * hi) = ov;
                }
        }
    }
}

// ============================ fallback (verified round-3 kernel) ============================
#define FB_LDS_BYTES 77824

__global__ __launch_bounds__(256, 2)
void attn_fwd_fb(const float* __restrict__ Q, const float* __restrict__ K,
                 const float* __restrict__ V, const int* __restrict__ M,
                 float* __restrict__ O)
{
    __shared__ __align__(128) char lds[FB_LDS_BYTES];

    const int tid  = threadIdx.x;
    const int lane = tid & 63;
    const int w    = tid >> 6;
    const int c    = lane & 15;
    const int g    = lane >> 4;
    const int qt   = blockIdx.x;
    const int b    = blockIdx.y;
    const int q0   = qt * 64;

    const int rbase = tid >> 5;
    const int c4    = tid & 31;
    const unsigned swk = (unsigned)(c4 * 8) ^ (unsigned)(rbase << 4);
    const int vd    = tid & 127;
    const int vk0   = (tid >> 7) * 32;

    short8 qf[4];
    {
        const float* qrow = Q + ((size_t)(b * S_LEN + q0 + w * 16 + c)) * DH;
        #pragma unroll
        for (int dk = 0; dk < 4; ++dk) {
            const float* p = qrow + dk * 32 + g * 8;
            float4 a  = *(const float4*)(p);
            float4 bb = *(const float4*)(p + 4);
            short8 f;
            f[0] = f2b(a.x * SCALE);  f[1] = f2b(a.y * SCALE);
            f[2] = f2b(a.z * SCALE);  f[3] = f2b(a.w * SCALE);
            f[4] = f2b(bb.x * SCALE); f[5] = f2b(bb.y * SCALE);
            f[6] = f2b(bb.z * SCALE); f[7] = f2b(bb.w * SCALE);
            qf[dk] = f;
        }
    }

    float m_run[4] = {-1e30f, -1e30f, -1e30f, -1e30f};
    float l_run[4] = {0.f, 0.f, 0.f, 0.f};
    floatx4 accO[8];
    #pragma unroll
    for (int i = 0; i < 8; ++i) accO[i] = (floatx4)(0.f);

    const float* Kb = K + (size_t)b * S_LEN * DH;
    const float* Vb = V + (size_t)b * S_LEN * DH;
    const int*   Mb = M + (size_t)b * S_LEN * S_LEN + (size_t)q0 * S_LEN;

    size_t moff[4];
    #pragma unroll
    for (int r = 0; r < 4; ++r)
        moff[r] = (size_t)(w * 16 + 4 * g + r) * S_LEN;

    float4 kreg[8];
    float  vreg[32];
    int    mreg[16];

    #pragma unroll
    for (int i = 0; i < 8; ++i)
        kreg[i] = *(const float4*)(Kb + (size_t)(i * 8 + rbase) * DH + c4 * 4);
    #pragma unroll
    for (int j = 0; j < 32; ++j)
        vreg[j] = Vb[(size_t)(vk0 + j) * DH + vd];
    #pragma unroll
    for (int r = 0; r < 4; ++r)
        #pragma unroll
        for (int n = 0; n < 4; ++n)
            mreg[r * 4 + n] = Mb[moff[r] + n * 16 + c];

    #pragma unroll
    for (int i = 0; i < 8; ++i) {
        float4 kv = kreg[i];
        unsigned long long kp =
              (unsigned long long)f2b(kv.x)
            | ((unsigned long long)f2b(kv.y) << 16)
            | ((unsigned long long)f2b(kv.z) << 32)
            | ((unsigned long long)f2b(kv.w) << 48);
        *(unsigned long long*)(lds + (i * 8 + rbase) * 256 + swk) = kp;
    }
    {
        char* vbase = lds + 32768 + vd * 144 + vk0 * 2;
        #pragma unroll
        for (int i = 0; i < 4; ++i) {
            short8 pk;
            #pragma unroll
            for (int e = 0; e < 8; ++e) pk[e] = f2b(vreg[i * 8 + e]);
            *(short8*)(vbase + i * 16) = pk;
        }
    }
    #pragma unroll
    for (int i = 0; i < 8; ++i)
        kreg[i] = *(const float4*)(Kb + (size_t)(BKV + i * 8 + rbase) * DH + c4 * 4);
    #pragma unroll
    for (int j = 0; j < 32; ++j)
        vreg[j] = Vb[(size_t)(BKV + vk0 + j) * DH + vd];

    __syncthreads();

    char* psw = lds + 69632 + w * 2048;

    for (int step = 0; step < NSTEP; ++step) {
        const int p = step & 1;
        const int kv0 = step * BKV;
        char* KHp = lds + p * 16384;
        char* VTp = lds + 32768 + p * 18432;

        floatx4 accS[4];
        #pragma unroll
        for (int n = 0; n < 4; ++n) accS[n] = (floatx4)(0.f);
        #pragma unroll
        for (int n = 0; n < 4; ++n) {
            const char* krow = KHp + (n * 16 + c) * 256;
            #pragma unroll
            for (int dk = 0; dk < 4; ++dk) {
                unsigned colb = (unsigned)(dk * 64 + g * 16) ^ (unsigned)((c & 7) << 4);
                short8 kf = *(const short8*)(krow + colb);
                accS[n] = __builtin_amdgcn_mfma_f32_16x16x32_bf16(qf[dk], kf, accS[n], 0, 0, 0);
            }
        }

        float pv[4][4];
        float corr[4];
        #pragma unroll
        for (int r = 0; r < 4; ++r) {
            float sv[4];
            #pragma unroll
            for (int n = 0; n < 4; ++n) {
                float s = accS[n][r];
                if (mreg[r * 4 + n]) s = -1e30f;
                sv[n] = s;
            }
            float tm = fmaxf(fmaxf(sv[0], sv[1]), fmaxf(sv[2], sv[3]));
            #pragma unroll
            for (int off = 1; off < 16; off <<= 1)
                tm = fmaxf(tm, __shfl_xor(tm, off, 64));
            float mn = fmaxf(m_run[r], tm);
            corr[r]  = __expf(m_run[r] - mn);
            m_run[r] = mn;
            float ts = 0.f;
            #pragma unroll
            for (int n = 0; n < 4; ++n) { pv[n][r] = __expf(sv[n] - mn); ts += pv[n][r]; }
            #pragma unroll
            for (int off = 1; off < 16; off <<= 1)
                ts += __shfl_xor(ts, off, 64);
            l_run[r] = l_run[r] * corr[r] + ts;
        }
        if (step + 1 < NSTEP) {
            const int kvn = kv0 + BKV;
            #pragma unroll
            for (int r = 0; r < 4; ++r)
                #pragma unroll
                for (int n = 0; n < 4; ++n)
                    mreg[r * 4 + n] = Mb[moff[r] + kvn + n * 16 + c];
        }

        #pragma unroll
        for (int s8 = 0; s8 < 8; ++s8) {
            floatx4 o = accO[s8];
            o[0] *= corr[0]; o[1] *= corr[1]; o[2] *= corr[2]; o[3] *= corr[3];
            accO[s8] = o;
        }

        #pragma unroll
        for (int r = 0; r < 4; ++r) {
            int rl = 4 * g + r;
            #pragma unroll
            for (int n = 0; n < 4; ++n) {
                unsigned colb = (unsigned)((n * 16 + c) * 2) ^ (unsigned)((rl & 7) << 4);
                *(unsigned short*)(psw + rl * 128 + colb) = f2b(pv[n][r]);
            }
        }

        #pragma unroll
        for (int sub = 0; sub < 2; ++sub) {
            unsigned colb = (unsigned)(sub * 64 + g * 16) ^ (unsigned)((c & 7) << 4);
            short8 pf = *(const short8*)(psw + c * 128 + colb);
            #pragma unroll
            for (int s8 = 0; s8 < 8; ++s8) {
                short8 vf = *(const short8*)(VTp + (s8 * 16 + c) * 144 + sub * 64 + g * 16);
                accO[s8] = __builtin_amdgcn_mfma_f32_16x16x32_bf16(pf, vf, accO[s8], 0, 0, 0);
            }
        }

        if (step + 1 < NSTEP) {
            char* KHn = lds + (p ^ 1) * 16384;
            char* VTn = lds + 32768 + (p ^ 1) * 18432;
            #pragma unroll
            for (int i = 0; i < 8; ++i) {
                float4 kv = kreg[i];
                unsigned long long kp =
                      (unsigned long long)f2b(kv.x)
                    | ((unsigned long long)f2b(kv.y) << 16)
                    | ((unsigned long long)f2b(kv.z) << 32)
                    | ((unsigned long long)f2b(kv.w) << 48);
                *(unsigned long long*)(KHn + (i * 8 + rbase) * 256 + swk) = kp;
            }
            char* vbase = VTn + vd * 144 + vk0 * 2;
            #pragma unroll
            for (int i = 0; i < 4; ++i) {
                short8 pk;
                #pragma unroll
                for (int e = 0; e < 8; ++e) pk[e] = f2b(vreg[i * 8 + e]);
                *(short8*)(vbase + i * 16) = pk;
            }
            if (step + 2 < NSTEP) {
                const int kvn2 = kv0 + 2 * BKV;
                #pragma unroll
                for (int i = 0; i < 8; ++i)
                    kreg[i] = *(const float4*)(Kb + (size_t)(kvn2 + i * 8 + rbase) * DH + c4 * 4);
                #pragma unroll
                for (int j = 0; j < 32; ++j)
                    vreg[j] = Vb[(size_t)(kvn2 + vk0 + j) * DH + vd];
            }
        }
        __syncthreads();
    }

    float inv[4];
    #pragma unroll
    for (int r = 0; r < 4; ++r) inv[r] = (l_run[r] > 0.f) ? 1.f / l_run[r] : 0.f;
    float* Ob = O + ((size_t)(b * S_LEN + q0 + w * 16)) * DH;
    #pragma unroll
    for (int s8 = 0; s8 < 8; ++s8) {
        #pragma unroll
        for (int r = 0; r < 4; ++r) {
            Ob[(size_t)(4 * g + r) * DH + s8 * 16 + c] = accO[s8][r] * inv[r];
        }
    }
}

extern "C" void kernel_launch(void* const* d_in, const int* in_sizes, int n_in,
                              void* d_out, int out_size, void* d_ws, size_t ws_size,
                              hipStream_t stream) {
    const float* Q = (const float*)d_in[0];
    const float* K = (const float*)d_in[1];
    const float* V = (const float*)d_in[2];
    const int*   M = (const int*)d_in[3];
    float*       O = (float*)d_out;

    const size_t elems    = (size_t)16 * S_LEN * DH;           // per K/V tensor
    const size_t kv_bytes = elems * sizeof(unsigned short);    // 8.39 MB each
    const size_t pm_bytes = (size_t)16 * S_LEN * 32 * 8;       // 8.39 MB
    if (ws_size >= 2 * kv_bytes + pm_bytes) {
        unsigned short*     KF = (unsigned short*)d_ws;
        unsigned short*     VF = (unsigned short*)d_ws + elems;
        unsigned long long* Pm = (unsigned long long*)((char*)d_ws + 2 * kv_bytes);
        kfrag_make<<<dim3(32, 16), dim3(256), 0, stream>>>(K, KF);
        vfrag_make<<<dim3(S_LEN / 32, DH / 32, 16), dim3(256), 0, stream>>>(V, VF);
        pack_mask<<<dim3(16 * S_LEN / 4), dim3(256), 0, stream>>>(M, Pm);
        attn_fwd<<<dim3(S_LEN / BQ, 16), dim3(256), 0, stream>>>(Q, KF, VF, Pm, O);
    } else {
        attn_fwd_fb<<<dim3(S_LEN / 64, 16), dim3(256), 0, stream>>>(Q, K, V, M, O);
    }
}